// Round 1
// baseline (169.462 us; speedup 1.0000x reference)
//
#include <hip/hip_runtime.h>
#include <math.h>

#define IMG_W 512
#define IMG_H 512
#define NIMG 16
#define HWSZ (IMG_W * IMG_H)          // 262144
#define CHWSZ (3 * HWSZ)              // 786432
#define PAD 7
#define NORM (1.0 / 4194304.0)        // 1 / (N*H*W)

__device__ __forceinline__ float f_lab(float t) {
    // t >= 0 always here. cbrt via hw log2/exp2; branch selected away for small t.
    float c = exp2f(log2f(t) * (1.0f / 3.0f));
    return (t > 0.008856f) ? c : fmaf(7.787f, t, 0.13793103448275862f);
}

__device__ __forceinline__ void rgb_to_luv(float r, float g, float b,
                                           float& l, float& u, float& v) {
    float x = 0.4124564f * r + 0.3575761f * g + 0.1804375f * b;
    float y = 0.2126729f * r + 0.7151522f * g + 0.0721750f * b;
    float z = 0.0193339f * r + 0.1191920f * g + 0.9503041f * b;
    x *= (1.0f / 0.95047f);
    z *= (1.0f / 1.08883f);
    float fx = f_lab(x), fy = f_lab(y), fz = f_lab(z);
    l = 116.0f * fy - 16.0f;
    u = 13.0f * l * (fx - fy);
    v = 13.0f * l * (fy - fz);
}

// One block per (n, h) row: compute LUV diff for the row, then 15-tap
// horizontal box sum (zero padding) from LDS, write to tmp (N,3,H,W).
__global__ __launch_bounds__(256) void luv_diff_hpass(
        const float* __restrict__ inp, const float* __restrict__ tgt,
        float* __restrict__ tmp) {
    __shared__ float d[3][IMG_W + 16];   // +8 halo each side, zeroed
    int blk = blockIdx.x;
    int n = blk >> 9;          // / 512
    int h = blk & 511;
    size_t base = (size_t)n * CHWSZ + (size_t)h * IMG_W;
    int tid = threadIdx.x;

    if (tid < 8) {
        #pragma unroll
        for (int c = 0; c < 3; ++c) {
            d[c][tid] = 0.0f;
            d[c][IMG_W + 8 + tid] = 0.0f;
        }
    }

    #pragma unroll
    for (int k = 0; k < 2; ++k) {
        int w = tid + k * 256;
        float r = inp[base + w];
        float g = inp[base + HWSZ + w];
        float b = inp[base + 2 * HWSZ + w];
        float l1, u1, v1;
        rgb_to_luv(r, g, b, l1, u1, v1);
        r = tgt[base + w];
        g = tgt[base + HWSZ + w];
        b = tgt[base + 2 * HWSZ + w];
        float l2, u2, v2;
        rgb_to_luv(r, g, b, l2, u2, v2);
        d[0][w + 8] = l1 - l2;
        d[1][w + 8] = u1 - u2;
        d[2][w + 8] = v1 - v2;
    }
    __syncthreads();

    #pragma unroll
    for (int k = 0; k < 2; ++k) {
        int w = tid + k * 256;
        float sl = 0.f, su = 0.f, sv = 0.f;
        #pragma unroll
        for (int j = 0; j < 15; ++j) {    // taps at w-7..w+7 → LDS idx w+1+j
            sl += d[0][w + 1 + j];
            su += d[1][w + 1 + j];
            sv += d[2][w + 1 + j];
        }
        tmp[base + w] = sl;
        tmp[base + HWSZ + w] = su;
        tmp[base + 2 * HWSZ + w] = sv;
    }
}

// Vertical 15-tap running-window sum down columns, square, reduce.
// Grid: 48 (n*c) × 2 (w strips of 256) × 8 (h segments of 64) = 768 blocks.
__global__ __launch_bounds__(256) void vpass_reduce(
        const float* __restrict__ tmp, double* __restrict__ acc) {
    int blk = blockIdx.x;
    int hseg = blk & 7;
    int wstrip = (blk >> 3) & 1;
    int nc = blk >> 4;                       // 0..47
    int w = wstrip * 256 + (int)threadIdx.x;
    const float* col = tmp + (size_t)nc * HWSZ + w;
    int h0 = hseg * 64;

    float sum = 0.f;
    int lo = h0 - PAD;
    if (lo < 0) lo = 0;
    for (int j = lo; j <= h0 + PAD; ++j)     // h0+7 <= 455, always in range
        sum += col[(size_t)j * IMG_W];

    float a = 0.f;
    #pragma unroll 4
    for (int i = 0; i < 64; ++i) {
        int h = h0 + i;
        a += sum * sum;
        int addr = h + 8, subr = h - 7;
        if (addr <= IMG_H - 1) sum += col[(size_t)addr * IMG_W];
        if (subr >= 0)         sum -= col[(size_t)subr * IMG_W];
    }

    // block reduction: wave shuffle then LDS across 4 waves
    #pragma unroll
    for (int off = 32; off > 0; off >>= 1)
        a += __shfl_down(a, off, 64);
    __shared__ float red[4];
    int lane = threadIdx.x & 63, wid = threadIdx.x >> 6;
    if (lane == 0) red[wid] = a;
    __syncthreads();
    if (threadIdx.x == 0) {
        float s = red[0] + red[1] + red[2] + red[3];
        atomicAdd(acc, (double)s);
    }
}

__global__ void zero_acc(double* acc) { *acc = 0.0; }

__global__ void finalize(const double* __restrict__ acc, float* __restrict__ out) {
    out[0] = (float)(*acc * NORM);
}

extern "C" void kernel_launch(void* const* d_in, const int* in_sizes, int n_in,
                              void* d_out, int out_size, void* d_ws, size_t ws_size,
                              hipStream_t stream) {
    const float* inp = (const float*)d_in[0];
    const float* tgt = (const float*)d_in[1];
    // d_in[2] is patch_size == 15, baked in at compile time.
    float* out = (float*)d_out;
    double* acc = (double*)d_ws;
    float* tmp = (float*)((char*)d_ws + 256);   // 50.3 MB temp after accumulator

    zero_acc<<<1, 1, 0, stream>>>(acc);
    luv_diff_hpass<<<NIMG * IMG_H, 256, 0, stream>>>(inp, tgt, tmp);
    vpass_reduce<<<768, 256, 0, stream>>>(tmp, acc);
    finalize<<<1, 1, 0, stream>>>(acc, out);
}

// Round 2
// 141.697 us; speedup vs baseline: 1.1959x; 1.1959x over previous
//
#include <hip/hip_runtime.h>
#include <math.h>

#define IMG_W 512
#define IMG_H 512
#define NIMG 16
#define HWSZ (IMG_W * IMG_H)          // 262144
#define CHWSZ (3 * HWSZ)              // 786432
#define NORM (1.0 / 4194304.0)        // 1 / (N*H*W)
#define ROWP 544                      // 528 data slots + pad (idx(527)=543)
#define NBLK_V 768                    // vpass grid

__device__ __forceinline__ int pidx(int w) { return w + (w >> 5); }  // 2-way max bank alias for stride-8 lanes

__device__ __forceinline__ float f_lab(float t) {
    float c = exp2f(log2f(t) * (1.0f / 3.0f));   // cbrt; t<=eps branch selected away (log(0)->-inf->exp2->0, no NaN)
    return (t > 0.008856f) ? c : fmaf(7.787f, t, 0.13793103448275862f);
}

__device__ __forceinline__ void rgb_to_luv(float r, float g, float b,
                                           float& l, float& u, float& v) {
    float x = 0.4124564f * r + 0.3575761f * g + 0.1804375f * b;
    float y = 0.2126729f * r + 0.7151522f * g + 0.0721750f * b;
    float z = 0.0193339f * r + 0.1191920f * g + 0.9503041f * b;
    x *= (1.0f / 0.95047f);
    z *= (1.0f / 1.08883f);
    float fx = f_lab(x), fy = f_lab(y), fz = f_lab(z);
    l = 116.0f * fy - 16.0f;
    u = 13.0f * l * (fx - fy);
    v = 13.0f * l * (fy - fz);
}

// Block = 4 image rows. Phase 1: float4 loads, LUV diff -> LDS (padded index).
// Phase 2: per-thread 8-px sliding-window horizontal 15-tap sum -> float4 stores.
__global__ __launch_bounds__(256) void luv_hpass2(
        const float* __restrict__ inp, const float* __restrict__ tgt,
        float* __restrict__ tmp) {
    __shared__ float d[3][4][ROWP];
    int blk = blockIdx.x;
    int n = blk >> 7;                 // 128 row-blocks per image
    int h0 = (blk & 127) << 2;
    int t = threadIdx.x;

    if (t < 192) {                    // zero halos: 3ch x 4rows x 16 slots
        int wslot = t & 15;
        int w = (wslot < 8) ? wslot : (512 + wslot);
        int rc = t >> 4;              // 0..11
        d[rc >> 2][rc & 3][pidx(w)] = 0.0f;
    }

    int p0 = t * 8;
    int r = p0 >> 9;                  // row within block (64 threads per row)
    int w0 = p0 & 511;
    size_t base = (size_t)n * CHWSZ + (size_t)(h0 + r) * IMG_W + w0;

    float dl[8], du[8], dv[8];
    {
        float R[8], G[8], B[8];
        *(float4*)&R[0] = *(const float4*)(inp + base);
        *(float4*)&R[4] = *(const float4*)(inp + base + 4);
        *(float4*)&G[0] = *(const float4*)(inp + base + HWSZ);
        *(float4*)&G[4] = *(const float4*)(inp + base + HWSZ + 4);
        *(float4*)&B[0] = *(const float4*)(inp + base + 2 * HWSZ);
        *(float4*)&B[4] = *(const float4*)(inp + base + 2 * HWSZ + 4);
        #pragma unroll
        for (int j = 0; j < 8; ++j)
            rgb_to_luv(R[j], G[j], B[j], dl[j], du[j], dv[j]);
        *(float4*)&R[0] = *(const float4*)(tgt + base);
        *(float4*)&R[4] = *(const float4*)(tgt + base + 4);
        *(float4*)&G[0] = *(const float4*)(tgt + base + HWSZ);
        *(float4*)&G[4] = *(const float4*)(tgt + base + HWSZ + 4);
        *(float4*)&B[0] = *(const float4*)(tgt + base + 2 * HWSZ);
        *(float4*)&B[4] = *(const float4*)(tgt + base + 2 * HWSZ + 4);
        #pragma unroll
        for (int j = 0; j < 8; ++j) {
            float l2, u2, v2;
            rgb_to_luv(R[j], G[j], B[j], l2, u2, v2);
            dl[j] -= l2; du[j] -= u2; dv[j] -= v2;
        }
    }
    #pragma unroll
    for (int j = 0; j < 8; ++j) {
        d[0][r][pidx(w0 + 8 + j)] = dl[j];
        d[1][r][pidx(w0 + 8 + j)] = du[j];
        d[2][r][pidx(w0 + 8 + j)] = dv[j];
    }
    __syncthreads();

    size_t obase = (size_t)n * CHWSZ + (size_t)(h0 + r) * IMG_W + w0;
    #pragma unroll
    for (int c = 0; c < 3; ++c) {
        float o[8];
        float s = 0.0f;
        #pragma unroll
        for (int j = 0; j < 15; ++j) s += d[c][r][pidx(w0 + 1 + j)];
        o[0] = s;
        #pragma unroll
        for (int k = 1; k < 8; ++k) {
            s += d[c][r][pidx(w0 + 15 + k)] - d[c][r][pidx(w0 + k)];
            o[k] = s;
        }
        *(float4*)(tmp + obase + (size_t)c * HWSZ)     = *(float4*)&o[0];
        *(float4*)(tmp + obase + (size_t)c * HWSZ + 4) = *(float4*)&o[4];
    }
}

// Vertical 15-tap running window. Software-pipelined: 16 add-rows + 16
// sub-rows batched as independent loads, then register-only updates.
template <bool GUARD>
__device__ __forceinline__ void vchunk(const float* __restrict__ col, int hb,
                                       float& sum, float& a) {
    float va[16], vs[16];
    #pragma unroll
    for (int j = 0; j < 16; ++j) {
        int ha = hb + j + 8;
        int hs = hb + j - 7;
        if (GUARD) {
            va[j] = (ha <= IMG_H - 1) ? col[(size_t)ha * IMG_W] : 0.0f;
            vs[j] = (hs >= 0)         ? col[(size_t)hs * IMG_W] : 0.0f;
        } else {
            va[j] = col[(size_t)ha * IMG_W];
            vs[j] = col[(size_t)hs * IMG_W];
        }
    }
    #pragma unroll
    for (int j = 0; j < 16; ++j) {
        a += sum * sum;
        sum += va[j] - vs[j];
    }
}

__global__ __launch_bounds__(256) void vpass_reduce2(
        const float* __restrict__ tmp, float* __restrict__ partial) {
    int blk = blockIdx.x;
    int half = blk & 1;
    int hseg = (blk >> 1) & 7;
    int nc = blk >> 4;                // 0..47
    int w = half * 256 + (int)threadIdx.x;
    const float* col = tmp + (size_t)nc * HWSZ + w;
    int h0 = hseg * 64;

    float sum = 0.0f;
    #pragma unroll
    for (int j = -7; j <= 7; ++j) {
        int h = h0 + j;
        if (h >= 0) sum += col[(size_t)h * IMG_W];   // h <= 455+7 < 512 always
    }

    float a = 0.0f;
    if (h0 >= 64 && h0 <= 384) {      // interior: branch-free deep-MLP path
        vchunk<false>(col, h0,      sum, a);
        vchunk<false>(col, h0 + 16, sum, a);
        vchunk<false>(col, h0 + 32, sum, a);
        vchunk<false>(col, h0 + 48, sum, a);
    } else {
        vchunk<true>(col, h0,      sum, a);
        vchunk<true>(col, h0 + 16, sum, a);
        vchunk<true>(col, h0 + 32, sum, a);
        vchunk<true>(col, h0 + 48, sum, a);
    }

    #pragma unroll
    for (int off = 32; off > 0; off >>= 1)
        a += __shfl_down(a, off, 64);
    __shared__ float red[4];
    int lane = threadIdx.x & 63, wid = threadIdx.x >> 6;
    if (lane == 0) red[wid] = a;
    __syncthreads();
    if (threadIdx.x == 0)
        partial[blk] = red[0] + red[1] + red[2] + red[3];
}

__global__ __launch_bounds__(256) void finalize2(
        const float* __restrict__ partial, float* __restrict__ out) {
    int t = threadIdx.x;
    float a = 0.0f;
    #pragma unroll
    for (int i = 0; i < NBLK_V; i += 256) a += partial[i + t];
    #pragma unroll
    for (int off = 32; off > 0; off >>= 1)
        a += __shfl_down(a, off, 64);
    __shared__ float red[4];
    int lane = t & 63, wid = t >> 6;
    if (lane == 0) red[wid] = a;
    __syncthreads();
    if (t == 0)
        out[0] = (float)((double)(red[0] + red[1] + red[2] + red[3]) * NORM);
}

extern "C" void kernel_launch(void* const* d_in, const int* in_sizes, int n_in,
                              void* d_out, int out_size, void* d_ws, size_t ws_size,
                              hipStream_t stream) {
    const float* inp = (const float*)d_in[0];
    const float* tgt = (const float*)d_in[1];
    float* out = (float*)d_out;
    float* partial = (float*)d_ws;                       // 768 floats
    float* tmp = (float*)((char*)d_ws + 4096);           // 50.3 MB temp

    luv_hpass2<<<NIMG * 128, 256, 0, stream>>>(inp, tgt, tmp);
    vpass_reduce2<<<NBLK_V, 256, 0, stream>>>(tmp, partial);
    finalize2<<<1, 256, 0, stream>>>(partial, out);
}

// Round 3
// 133.635 us; speedup vs baseline: 1.2681x; 1.0603x over previous
//
#include <hip/hip_runtime.h>
#include <math.h>

#define IMG_W 512
#define IMG_H 512
#define NIMG 16
#define HWSZ (IMG_W * IMG_H)          // 262144
#define CHWSZ (3 * HWSZ)              // 786432
#define NORM (1.0 / 4194304.0)        // 1 / (N*H*W)
#define NBLK_V 1536                   // 48 nc * 32 hsegs

__device__ __forceinline__ float f_lab(float t) {
    float c = exp2f(log2f(t) * (1.0f / 3.0f));   // cbrt; small-t branch selected away
    return (t > 0.008856f) ? c : fmaf(7.787f, t, 0.13793103448275862f);
}

__device__ __forceinline__ void rgb_to_luv(float r, float g, float b,
                                           float& l, float& u, float& v) {
    float x = 0.4124564f * r + 0.3575761f * g + 0.1804375f * b;
    float y = 0.2126729f * r + 0.7151522f * g + 0.0721750f * b;
    float z = 0.0193339f * r + 0.1191920f * g + 0.9503041f * b;
    x *= (1.0f / 0.95047f);
    z *= (1.0f / 1.08883f);
    float fx = f_lab(x), fy = f_lab(y), fz = f_lab(z);
    l = 116.0f * fy - 16.0f;
    u = 13.0f * l * (fx - fy);
    v = 13.0f * l * (fy - fz);
}

__device__ __forceinline__ unsigned short f2bf(float x) {   // RNE f32->bf16
    unsigned int u = __float_as_uint(x);
    u += 0x7fff + ((u >> 16) & 1);
    return (unsigned short)(u >> 16);
}

// 15-tap horizontal sliding window across a wave-owned row (8 px/lane),
// halo from adjacent lanes via shuffles; zero padding at row ends.
__device__ __forceinline__ void hslide(const float d[8], float o[8], int lane) {
    float L[7], R[7];
    #pragma unroll
    for (int j = 0; j < 7; ++j) {
        float l = __shfl_up(d[j + 1], 1, 64);    // left lane's px w0-7..w0-1
        L[j] = (lane == 0) ? 0.0f : l;
        float r = __shfl_down(d[j], 1, 64);      // right lane's px w0+8..w0+14
        R[j] = (lane == 63) ? 0.0f : r;
    }
    float s = 0.0f;
    #pragma unroll
    for (int j = 0; j < 7; ++j) s += L[j];
    #pragma unroll
    for (int j = 0; j < 8; ++j) s += d[j];
    o[0] = s;                                    // window w0-7..w0+7
    #pragma unroll
    for (int k = 1; k < 8; ++k) o[k] = o[k - 1] + R[k - 1] - L[k - 1];
}

__device__ __forceinline__ uint4 pack8(const float o[8]) {
    uint4 p;
    p.x = (unsigned)f2bf(o[0]) | ((unsigned)f2bf(o[1]) << 16);
    p.y = (unsigned)f2bf(o[2]) | ((unsigned)f2bf(o[3]) << 16);
    p.z = (unsigned)f2bf(o[4]) | ((unsigned)f2bf(o[5]) << 16);
    p.w = (unsigned)f2bf(o[6]) | ((unsigned)f2bf(o[7]) << 16);
    return p;
}

// Block = 4 waves = 4 rows; wave owns a full 512-px row (8 px/lane).
// No LDS, no barrier. Output: bf16 h-passed diff, layout (48, 512, 512).
__global__ __launch_bounds__(256) void luv_hpass3(
        const float* __restrict__ inp, const float* __restrict__ tgt,
        unsigned short* __restrict__ tmp) {
    int blk = blockIdx.x;
    int n = blk >> 7;                            // 128 row-quads per image
    int lane = threadIdx.x & 63;
    int h = ((blk & 127) << 2) | (threadIdx.x >> 6);
    int w0 = lane << 3;
    size_t base = (size_t)n * CHWSZ + (size_t)h * IMG_W + w0;

    float dl[8], du[8], dv[8];
    {
        float R[8], G[8], B[8];
        *(float4*)&R[0] = *(const float4*)(inp + base);
        *(float4*)&R[4] = *(const float4*)(inp + base + 4);
        *(float4*)&G[0] = *(const float4*)(inp + base + HWSZ);
        *(float4*)&G[4] = *(const float4*)(inp + base + HWSZ + 4);
        *(float4*)&B[0] = *(const float4*)(inp + base + 2 * HWSZ);
        *(float4*)&B[4] = *(const float4*)(inp + base + 2 * HWSZ + 4);
        #pragma unroll
        for (int j = 0; j < 8; ++j)
            rgb_to_luv(R[j], G[j], B[j], dl[j], du[j], dv[j]);
        *(float4*)&R[0] = *(const float4*)(tgt + base);
        *(float4*)&R[4] = *(const float4*)(tgt + base + 4);
        *(float4*)&G[0] = *(const float4*)(tgt + base + HWSZ);
        *(float4*)&G[4] = *(const float4*)(tgt + base + HWSZ + 4);
        *(float4*)&B[0] = *(const float4*)(tgt + base + 2 * HWSZ);
        *(float4*)&B[4] = *(const float4*)(tgt + base + 2 * HWSZ + 4);
        #pragma unroll
        for (int j = 0; j < 8; ++j) {
            float l2, u2, v2;
            rgb_to_luv(R[j], G[j], B[j], l2, u2, v2);
            dl[j] -= l2; du[j] -= u2; dv[j] -= v2;
        }
    }

    float o[8];
    hslide(dl, o, lane);
    *reinterpret_cast<uint4*>(tmp + base) = pack8(o);
    hslide(du, o, lane);
    *reinterpret_cast<uint4*>(tmp + base + HWSZ) = pack8(o);
    hslide(dv, o, lane);
    *reinterpret_cast<uint4*>(tmp + base + 2 * HWSZ) = pack8(o);
}

__device__ __forceinline__ void unpack8(uint4 v, float f[8]) {
    f[0] = __uint_as_float(v.x << 16);
    f[1] = __uint_as_float(v.x & 0xffff0000u);
    f[2] = __uint_as_float(v.y << 16);
    f[3] = __uint_as_float(v.y & 0xffff0000u);
    f[4] = __uint_as_float(v.z << 16);
    f[5] = __uint_as_float(v.z & 0xffff0000u);
    f[6] = __uint_as_float(v.w << 16);
    f[7] = __uint_as_float(v.w & 0xffff0000u);
}

template <bool GLO>
__device__ __forceinline__ void vprime(const unsigned short* __restrict__ col,
                                       int h0, float W[8]) {
    #pragma unroll
    for (int j = 0; j < 15; ++j) {
        int h = h0 - 7 + j;
        if (GLO && h < 0) continue;              // resolved at unroll time
        uint4 v = *(const uint4*)(col + (size_t)h * IMG_W);
        float a[8];
        unpack8(v, a);
        #pragma unroll
        for (int c = 0; c < 8; ++c) W[c] += a[c];
    }
}

// 8 row-iterations: batch 16 independent uint4 loads, then register updates.
template <bool GLO, bool GHI>
__device__ __forceinline__ void vchunk8(const unsigned short* __restrict__ col,
                                        int hb, float W[8], float& acc) {
    const uint4 z = make_uint4(0u, 0u, 0u, 0u);
    uint4 va[8], vs[8];
    #pragma unroll
    for (int j = 0; j < 8; ++j) {
        int ha = hb + j + 8, hs = hb + j - 7;
        va[j] = (GHI && ha >= IMG_H) ? z : *(const uint4*)(col + (size_t)ha * IMG_W);
        vs[j] = (GLO && hs < 0)      ? z : *(const uint4*)(col + (size_t)hs * IMG_W);
    }
    #pragma unroll
    for (int j = 0; j < 8; ++j) {
        float a[8], s[8];
        unpack8(va[j], a);
        unpack8(vs[j], s);
        #pragma unroll
        for (int c = 0; c < 8; ++c) {
            acc += W[c] * W[c];                  // square window centered at hb+j
            W[c] += a[c] - s[c];                 // advance to hb+j+1
        }
    }
}

// One wave per block; thread owns 8 bf16 columns (one uint4 per row).
// Grid: 48 nc * 32 hsegs of 16 output rows.
__global__ __launch_bounds__(64) void vpass3(
        const unsigned short* __restrict__ tmp, float* __restrict__ partial) {
    int blk = blockIdx.x;
    int hseg = blk & 31;
    int nc = blk >> 5;                           // 0..47
    int t = threadIdx.x;
    const unsigned short* col = tmp + (size_t)nc * HWSZ + (t << 3);
    int h0 = hseg << 4;

    float W[8] = {0.f, 0.f, 0.f, 0.f, 0.f, 0.f, 0.f, 0.f};
    float acc = 0.0f;

    if (hseg == 0) {
        vprime<true>(col, h0, W);
        vchunk8<true, false>(col, h0, W, acc);       // rows 0..7   (hs<0 guarded)
        vchunk8<false, false>(col, h0 + 8, W, acc);  // rows 8..15
    } else if (hseg == 31) {
        vprime<false>(col, h0, W);
        vchunk8<false, false>(col, h0, W, acc);      // rows 496..503 (ha<=511)
        vchunk8<false, true>(col, h0 + 8, W, acc);   // rows 504..511 (ha>=512 guarded)
    } else {
        vprime<false>(col, h0, W);
        vchunk8<false, false>(col, h0, W, acc);
        vchunk8<false, false>(col, h0 + 8, W, acc);
    }

    #pragma unroll
    for (int off = 32; off > 0; off >>= 1)
        acc += __shfl_down(acc, off, 64);
    if (t == 0) partial[blk] = acc;
}

__global__ __launch_bounds__(256) void finalize3(
        const float* __restrict__ partial, float* __restrict__ out) {
    int t = threadIdx.x;
    float a = 0.0f;
    #pragma unroll
    for (int i = 0; i < NBLK_V; i += 256) a += partial[i + t];
    #pragma unroll
    for (int off = 32; off > 0; off >>= 1)
        a += __shfl_down(a, off, 64);
    __shared__ float red[4];
    int lane = t & 63, wid = t >> 6;
    if (lane == 0) red[wid] = a;
    __syncthreads();
    if (t == 0)
        out[0] = (float)((double)(red[0] + red[1] + red[2] + red[3]) * NORM);
}

extern "C" void kernel_launch(void* const* d_in, const int* in_sizes, int n_in,
                              void* d_out, int out_size, void* d_ws, size_t ws_size,
                              hipStream_t stream) {
    const float* inp = (const float*)d_in[0];
    const float* tgt = (const float*)d_in[1];
    float* out = (float*)d_out;
    float* partial = (float*)d_ws;                         // 1536 floats
    unsigned short* tmp = (unsigned short*)((char*)d_ws + 8192);  // 25.2 MB bf16 temp

    luv_hpass3<<<NIMG * 128, 256, 0, stream>>>(inp, tgt, tmp);
    vpass3<<<NBLK_V, 64, 0, stream>>>(tmp, partial);
    finalize3<<<1, 256, 0, stream>>>(partial, out);
}